// Round 15
// baseline (616.492 us; speedup 1.0000x reference)
//
#include <hip/hip_runtime.h>
#include <cstdint>

// ---------------------------------------------------------------------------
// Mamba block. GEMM1: 256^2/BK=64 8-wave pipelined kernel (R9 schedule,
// 128KB LDS, 1 blk/CU). GEMM4: 256^2/BK=32 2-phase variant (64KB LDS,
// __launch_bounds__(512,4) -> 2 blk/CU) with split-K=8 bf16 partials
// (+reduce8_out_bf) -- m114 cross-block overlap covers barrier drains.
// GEMM2: m97 split-K=8 (+fused reduce->dbc,dt_bf). GEMM3: m97 +bias/softplus,
// fp32 delta. Scan: chunked 2-pass, bf16 xc/z, fast dA path.
// ---------------------------------------------------------------------------

typedef __bf16 bf16x8 __attribute__((ext_vector_type(8)));
typedef float f32x4 __attribute__((ext_vector_type(4)));

__device__ __forceinline__ unsigned short f2bf(float f) {
  uint32_t u = __float_as_uint(f);
  u += 0x7FFFu + ((u >> 16) & 1u);   // round-to-nearest-even
  return (unsigned short)(u >> 16);
}

__device__ __forceinline__ float bf2f(unsigned short v) {
  return __uint_as_float(((uint32_t)v) << 16);
}

__device__ __forceinline__ float silu_f(float v) {
  return v / (1.f + __expf(-v));
}

__device__ __forceinline__ float softplus_f(float v) {
  return (v > 20.f) ? v : log1pf(__expf(v));
}

// ---------------- fused cast kernel (all bf16 operand prep) ----------------
__global__ void cast_all(const float* __restrict__ x, const float* __restrict__ W_in,
                         const float* __restrict__ W_out, const float* __restrict__ W_dt,
                         const float* __restrict__ W_x,
                         unsigned short* __restrict__ x_bf, unsigned short* __restrict__ Win_bf,
                         unsigned short* __restrict__ Wout_bf, unsigned short* __restrict__ Wdt_bf,
                         unsigned short* __restrict__ Wx_bf) {
  int i = blockIdx.x * 256 + threadIdx.x;   // over 7,733,248 float4 groups
  const float4* s4; ushort4* d4; int j;
  if (i < 1048576)      { s4 = (const float4*)x;     d4 = (ushort4*)x_bf;    j = i; }
  else if (i < 5242880) { s4 = (const float4*)W_in;  d4 = (ushort4*)Win_bf;  j = i - 1048576; }
  else if (i < 7340032) { s4 = (const float4*)W_out; d4 = (ushort4*)Wout_bf; j = i - 5242880; }
  else if (i < 7471104) { s4 = (const float4*)W_dt;  d4 = (ushort4*)Wdt_bf;  j = i - 7340032; }
  else {
    j = i - 7471104;
    ushort4 o = {0, 0, 0, 0};
    if (j < 163840) {   // 160*4096/4
      float4 v = ((const float4*)W_x)[j];
      o.x = f2bf(v.x); o.y = f2bf(v.y); o.z = f2bf(v.z); o.w = f2bf(v.w);
    }
    ((ushort4*)Wx_bf)[j] = o;
    return;
  }
  float4 v = s4[j];
  ushort4 o; o.x = f2bf(v.x); o.y = f2bf(v.y); o.z = f2bf(v.z); o.w = f2bf(v.w);
  d4[j] = o;
}

// ---------------- m97-style bf16 MFMA GEMM (128^2, BK=32, split-K) --------
#define BM 128
#define BN 128
#define BKK 32

__device__ __forceinline__ void stage_tile(const unsigned short* __restrict__ G,
                                           int ldK, int g0, int k0,
                                           unsigned short* lds, int wave, int lane) {
#pragma unroll
  for (int c = 0; c < 2; ++c) {
    int row = c * 64 + wave * 16 + (lane >> 2);
    int col = (lane & 3) * 8;
    const unsigned short* src = G + (size_t)(g0 + row) * ldK + (k0 + col);
    unsigned short* dst = lds + c * 2048 + wave * 512;  // ushort units
    __builtin_amdgcn_global_load_lds((__attribute__((address_space(1))) void*)(src),
                                     (__attribute__((address_space(3))) void*)(dst),
                                     16, 0, 0);
  }
}

__global__ __launch_bounds__(256)
void gemm_bt(const unsigned short* __restrict__ A, const unsigned short* __restrict__ B,
             float* __restrict__ C, int M, int N, int ldK, int kchunk,
             const float* __restrict__ bias_sp) {
  __shared__ unsigned short As[BM * BKK];
  __shared__ unsigned short Bs[BN * BKK];
  const int tid = threadIdx.x;
  const int wave = tid >> 6, lane = tid & 63;
  const int wr = wave >> 1, wc = wave & 1;
  const int m0 = blockIdx.y * BM, n0 = blockIdx.x * BN;
  const int lr = lane & 15, lg = lane >> 4;
  const int kb = blockIdx.z * kchunk, ke = kb + kchunk;
  C += (size_t)blockIdx.z * M * N;

  f32x4 zero = {0.f, 0.f, 0.f, 0.f};
  f32x4 acc[4][4];
#pragma unroll
  for (int i = 0; i < 4; ++i)
#pragma unroll
    for (int j = 0; j < 4; ++j) acc[i][j] = zero;

  for (int k0 = kb; k0 < ke; k0 += BKK) {
    stage_tile(A, ldK, m0, k0, As, wave, lane);
    stage_tile(B, ldK, n0, k0, Bs, wave, lane);
    __syncthreads();
    bf16x8 af[4], bfr[4];
#pragma unroll
    for (int i = 0; i < 4; ++i)
      af[i] = *reinterpret_cast<const bf16x8*>(&As[(wr * 64 + i * 16 + lr) * BKK + lg * 8]);
#pragma unroll
    for (int j = 0; j < 4; ++j)
      bfr[j] = *reinterpret_cast<const bf16x8*>(&Bs[(wc * 64 + j * 16 + lr) * BKK + lg * 8]);
#pragma unroll
    for (int i = 0; i < 4; ++i)
#pragma unroll
      for (int j = 0; j < 4; ++j)
        acc[i][j] = __builtin_amdgcn_mfma_f32_16x16x32_bf16(af[i], bfr[j], acc[i][j], 0, 0, 0);
    __syncthreads();
  }

#pragma unroll
  for (int i = 0; i < 4; ++i) {
#pragma unroll
    for (int j = 0; j < 4; ++j) {
      int mrow = m0 + wr * 64 + i * 16 + lg * 4;
      int ncol = n0 + wc * 64 + j * 16 + lr;
      if (bias_sp) {
        float bv = bias_sp[ncol];
#pragma unroll
        for (int r = 0; r < 4; ++r)
          C[(size_t)(mrow + r) * N + ncol] = softplus_f(acc[i][j][r] + bv);
      } else {
#pragma unroll
        for (int r = 0; r < 4; ++r)
          C[(size_t)(mrow + r) * N + ncol] = acc[i][j][r];
      }
    }
  }
}

// split-K reducers --------------------------------------------------------
__global__ void reduce8_dbc(const float* __restrict__ p, float* __restrict__ dbc,
                            unsigned short* __restrict__ dt_bf) {
  int i = blockIdx.x * 256 + threadIdx.x;   // over 524288
  float s = 0.f;
#pragma unroll
  for (int c = 0; c < 8; ++c) s += p[(size_t)c * 524288 + i];
  dbc[i] = s;
  int col = i & 255;
  if (col < 128) dt_bf[(size_t)(i >> 8) * 128 + col] = f2bf(s);
}

// GEMM4: out = sum of 8 bf16 partial planes of [2048][2048].
__global__ void reduce8_out_bf(const unsigned short* __restrict__ p, float* __restrict__ out) {
  int i = blockIdx.x * 256 + threadIdx.x;   // over 1048576 ushort4 groups
  const ushort4* p4 = reinterpret_cast<const ushort4*>(p);
  float4 r = {0.f, 0.f, 0.f, 0.f};
#pragma unroll
  for (int c = 0; c < 8; ++c) {
    ushort4 a = p4[i + (size_t)c * 1048576];
    r.x += bf2f(a.x); r.y += bf2f(a.y); r.z += bf2f(a.z); r.w += bf2f(a.w);
  }
  reinterpret_cast<float4*>(out)[i] = r;
}

// ---------------- 256^2-tile BK=64 pipelined GEMM (R9 schedule) ------------
// 128KB LDS, 1 blk/CU. Per tile t: 4 phases; reads 10/2/10/2; stage quantum
// q at phase q; waits vmcnt(6)/(4)/-/(4). Used for GEMM1.
template <typename OT>
__global__ __launch_bounds__(512, 2)
void gemm_bt_8ph(const unsigned short* __restrict__ A,
                 const unsigned short* __restrict__ B,
                 OT* __restrict__ C, int M, int N, int K, int nbm, int kchunk) {
  __shared__ unsigned short As[2][16384];   // [buf][ks*8192 + row*32 + col]
  __shared__ unsigned short Bs[2][16384];
  const int tid = threadIdx.x;
  const int wid = tid >> 6, lane = tid & 63;
  const int wr = wid >> 2, wc = wid & 3;     // 2 x 4 waves
  const int lr = lane & 15, lg = lane >> 4;

  const int cpx = gridDim.x >> 3;
  const int x = blockIdx.x;
  const int wg = (x & 7) * cpx + (x >> 3);
  const int bm = wg % nbm, bn = wg / nbm;
  const int m0 = bm * 256, n0 = bn * 256;
  const int kb = blockIdx.z * kchunk;
  C += (size_t)blockIdx.z * M * N;

  f32x4 acc[8][4];
  f32x4 zero = {0.f, 0.f, 0.f, 0.f};
#pragma unroll
  for (int i = 0; i < 8; ++i)
#pragma unroll
    for (int j = 0; j < 4; ++j) acc[i][j] = zero;

  const int nt = kchunk / 64;

  auto QUANT = [&](int t, int q) {
    const int buf = t & 1;
    const int ks = q >> 1;
    const unsigned short* G = (q & 1) ? B : A;
    const int g0 = (q & 1) ? n0 : m0;
    unsigned short* lds = ((q & 1) ? &Bs[buf][0] : &As[buf][0]) + ks * 8192;
    const int k0 = kb + t * 64 + ks * 32;
#pragma unroll
    for (int r = 0; r < 2; ++r) {
      int row = r * 128 + (tid >> 2);
      int scol = ((tid & 3) * 8) ^ (((row >> 1) & 3) << 3);
      const unsigned short* src = G + (size_t)(g0 + row) * K + (k0 + scol);
      __builtin_amdgcn_global_load_lds(
          (__attribute__((address_space(1))) const void*)(src),
          (__attribute__((address_space(3))) void*)(lds + r * 4096 + tid * 8),
          16, 0, 0);
    }
  };

  auto RD_A = [&](int buf, int ks, int mf) -> bf16x8 {
    int row = wr * 128 + mf * 16 + lr;
    int col = (lg * 8) ^ (((row >> 1) & 3) << 3);
    return *reinterpret_cast<const bf16x8*>(&As[buf][ks * 8192 + row * 32 + col]);
  };
  auto RD_B = [&](int buf, int ks, int nf) -> bf16x8 {
    int row = wc * 64 + nf * 16 + lr;
    int col = (lg * 8) ^ (((row >> 1) & 3) << 3);
    return *reinterpret_cast<const bf16x8*>(&Bs[buf][ks * 8192 + row * 32 + col]);
  };

  QUANT(0, 0); QUANT(0, 1); QUANT(0, 2); QUANT(0, 3);
  asm volatile("s_waitcnt vmcnt(4)" ::: "memory");
  __builtin_amdgcn_s_barrier();

  bf16x8 a[8], b[4];
  for (int t = 0; t < nt; ++t) {
    const int buf = t & 1;
    const bool pf = (t + 1 < nt);
    // ---------------- ph0 (ks0, nf 0-1) ----------------
#pragma unroll
    for (int mf = 0; mf < 8; ++mf) a[mf] = RD_A(buf, 0, mf);
    b[0] = RD_B(buf, 0, 0); b[1] = RD_B(buf, 0, 1);
    if (pf) {
      QUANT(t + 1, 0);
      asm volatile("s_waitcnt vmcnt(6)" ::: "memory");
    } else {
      asm volatile("s_waitcnt vmcnt(4)" ::: "memory");
    }
    __builtin_amdgcn_s_barrier();
    asm volatile("s_waitcnt lgkmcnt(0)" ::: "memory");
    __builtin_amdgcn_sched_barrier(0);
    __builtin_amdgcn_s_setprio(1);
#pragma unroll
    for (int nf = 0; nf < 2; ++nf)
#pragma unroll
      for (int mf = 0; mf < 8; ++mf)
        acc[mf][nf] = __builtin_amdgcn_mfma_f32_16x16x32_bf16(a[mf], b[nf], acc[mf][nf], 0, 0, 0);
    __builtin_amdgcn_s_setprio(0);
    __builtin_amdgcn_s_barrier();
    // ---------------- ph1 (ks0, nf 2-3) ----------------
    b[2] = RD_B(buf, 0, 2); b[3] = RD_B(buf, 0, 3);
    if (pf) {
      QUANT(t + 1, 1);
      asm volatile("s_waitcnt vmcnt(4)" ::: "memory");
    } else {
      asm volatile("s_waitcnt vmcnt(0)" ::: "memory");
    }
    __builtin_amdgcn_s_barrier();
    asm volatile("s_waitcnt lgkmcnt(0)" ::: "memory");
    __builtin_amdgcn_sched_barrier(0);
    __builtin_amdgcn_s_setprio(1);
#pragma unroll
    for (int nf = 2; nf < 4; ++nf)
#pragma unroll
      for (int mf = 0; mf < 8; ++mf)
        acc[mf][nf] = __builtin_amdgcn_mfma_f32_16x16x32_bf16(a[mf], b[nf], acc[mf][nf], 0, 0, 0);
    __builtin_amdgcn_s_setprio(0);
    __builtin_amdgcn_s_barrier();
    // ---------------- ph2 (ks1, nf 0-1) ----------------
#pragma unroll
    for (int mf = 0; mf < 8; ++mf) a[mf] = RD_A(buf, 1, mf);
    b[0] = RD_B(buf, 1, 0); b[1] = RD_B(buf, 1, 1);
    if (pf) QUANT(t + 1, 2);
    __builtin_amdgcn_s_barrier();
    asm volatile("s_waitcnt lgkmcnt(0)" ::: "memory");
    __builtin_amdgcn_sched_barrier(0);
    __builtin_amdgcn_s_setprio(1);
#pragma unroll
    for (int nf = 0; nf < 2; ++nf)
#pragma unroll
      for (int mf = 0; mf < 8; ++mf)
        acc[mf][nf] = __builtin_amdgcn_mfma_f32_16x16x32_bf16(a[mf], b[nf], acc[mf][nf], 0, 0, 0);
    __builtin_amdgcn_s_setprio(0);
    __builtin_amdgcn_s_barrier();
    // ---------------- ph3 (ks1, nf 2-3) ----------------
    b[2] = RD_B(buf, 1, 2); b[3] = RD_B(buf, 1, 3);
    if (pf) {
      QUANT(t + 1, 3);
      asm volatile("s_waitcnt vmcnt(4)" ::: "memory");
    }
    __builtin_amdgcn_s_barrier();
    asm volatile("s_waitcnt lgkmcnt(0)" ::: "memory");
    __builtin_amdgcn_sched_barrier(0);
    __builtin_amdgcn_s_setprio(1);
#pragma unroll
    for (int nf = 2; nf < 4; ++nf)
#pragma unroll
      for (int mf = 0; mf < 8; ++mf)
        acc[mf][nf] = __builtin_amdgcn_mfma_f32_16x16x32_bf16(a[mf], b[nf], acc[mf][nf], 0, 0, 0);
    __builtin_amdgcn_s_setprio(0);
    __builtin_amdgcn_s_barrier();
  }

  // Epilogue: C/D layout col=lane&15, row=(lane>>4)*4+reg (m89-verified)
#pragma unroll
  for (int mf = 0; mf < 8; ++mf) {
#pragma unroll
    for (int nf = 0; nf < 4; ++nf) {
      int mrow = m0 + wr * 128 + mf * 16 + lg * 4;
      int ncol = n0 + wc * 64 + nf * 16 + lr;
#pragma unroll
      for (int r = 0; r < 4; ++r) {
        if constexpr (sizeof(OT) == 2)
          C[(size_t)(mrow + r) * N + ncol] = (OT)f2bf(acc[mf][nf][r]);
        else
          C[(size_t)(mrow + r) * N + ncol] = (OT)acc[mf][nf][r];
      }
    }
  }
}

// ---------------- 256^2-tile BK=32 2-phase GEMM (64KB LDS, 2 blk/CU) -------
// Same wave geometry/swizzle as 8ph; single K-slice per tile, 2 phases:
//  ph0: reads a[0..7],b01 (10); issue Q_A(t+1); vmcnt(2); bar; lgkm0;
//       16 MFMA (nf0-1); bar
//  ph1: reads b23 (2); issue Q_B(t+1); bar; lgkm0; 16 MFMA (nf2-3); bar
// vmcnt(2) at ph0 forces both tile-t quanta (newest 2 = Q_A(t+1) in
// flight); double-buffer makes refills overwrite-safe (opposite buffer).
// Thin 1-2 phase prefetch lead is covered by the co-resident block
// (launch_bounds (512,4): 64KB LDS + <=128 VGPR -> 2 blocks/CU).
template <typename OT>
__global__ __launch_bounds__(512, 4)
void gemm_bt_2ph(const unsigned short* __restrict__ A,
                 const unsigned short* __restrict__ B,
                 OT* __restrict__ C, int M, int N, int K, int nbm, int kchunk) {
  __shared__ unsigned short As[2][8192];   // [buf][row*32 + col], 256 rows
  __shared__ unsigned short Bs[2][8192];
  const int tid = threadIdx.x;
  const int wid = tid >> 6, lane = tid & 63;
  const int wr = wid >> 2, wc = wid & 3;     // 2 x 4 waves
  const int lr = lane & 15, lg = lane >> 4;

  const int cpx = gridDim.x >> 3;
  const int x = blockIdx.x;
  const int wg = (x & 7) * cpx + (x >> 3);
  const int bm = wg % nbm, bn = wg / nbm;
  const int m0 = bm * 256, n0 = bn * 256;
  const int kb = blockIdx.z * kchunk;
  C += (size_t)blockIdx.z * M * N;

  f32x4 acc[8][4];
  f32x4 zero = {0.f, 0.f, 0.f, 0.f};
#pragma unroll
  for (int i = 0; i < 8; ++i)
#pragma unroll
    for (int j = 0; j < 4; ++j) acc[i][j] = zero;

  const int nt = kchunk / 32;

  auto QUANT = [&](int t, int isB) {
    const int buf = t & 1;
    const unsigned short* G = isB ? B : A;
    const int g0 = isB ? n0 : m0;
    unsigned short* lds = isB ? &Bs[buf][0] : &As[buf][0];
    const int k0 = kb + t * 32;
#pragma unroll
    for (int r = 0; r < 2; ++r) {
      int row = r * 128 + (tid >> 2);
      int scol = ((tid & 3) * 8) ^ (((row >> 1) & 3) << 3);
      const unsigned short* src = G + (size_t)(g0 + row) * K + (k0 + scol);
      __builtin_amdgcn_global_load_lds(
          (__attribute__((address_space(1))) const void*)(src),
          (__attribute__((address_space(3))) void*)(lds + r * 4096 + tid * 8),
          16, 0, 0);
    }
  };

  auto RD_A = [&](int buf, int mf) -> bf16x8 {
    int row = wr * 128 + mf * 16 + lr;
    int col = (lg * 8) ^ (((row >> 1) & 3) << 3);
    return *reinterpret_cast<const bf16x8*>(&As[buf][row * 32 + col]);
  };
  auto RD_B = [&](int buf, int nf) -> bf16x8 {
    int row = wc * 64 + nf * 16 + lr;
    int col = (lg * 8) ^ (((row >> 1) & 3) << 3);
    return *reinterpret_cast<const bf16x8*>(&Bs[buf][row * 32 + col]);
  };

  // prologue: tile 0 (loop's t=0.ph0 vmcnt(2) forces these)
  QUANT(0, 0); QUANT(0, 1);
  __builtin_amdgcn_s_barrier();

  bf16x8 a[8], b[4];
  for (int t = 0; t < nt; ++t) {
    const int buf = t & 1;
    const bool pf = (t + 1 < nt);
    // ---------------- ph0 (nf 0-1) ----------------
#pragma unroll
    for (int mf = 0; mf < 8; ++mf) a[mf] = RD_A(buf, mf);
    b[0] = RD_B(buf, 0); b[1] = RD_B(buf, 1);
    if (pf) {
      QUANT(t + 1, 0);
      asm volatile("s_waitcnt vmcnt(2)" ::: "memory");
    } else {
      asm volatile("s_waitcnt vmcnt(0)" ::: "memory");
    }
    __builtin_amdgcn_s_barrier();
    asm volatile("s_waitcnt lgkmcnt(0)" ::: "memory");
    __builtin_amdgcn_sched_barrier(0);
    __builtin_amdgcn_s_setprio(1);
#pragma unroll
    for (int nf = 0; nf < 2; ++nf)
#pragma unroll
      for (int mf = 0; mf < 8; ++mf)
        acc[mf][nf] = __builtin_amdgcn_mfma_f32_16x16x32_bf16(a[mf], b[nf], acc[mf][nf], 0, 0, 0);
    __builtin_amdgcn_s_setprio(0);
    __builtin_amdgcn_s_barrier();
    // ---------------- ph1 (nf 2-3) ----------------
    b[2] = RD_B(buf, 2); b[3] = RD_B(buf, 3);
    if (pf) QUANT(t + 1, 1);
    __builtin_amdgcn_s_barrier();
    asm volatile("s_waitcnt lgkmcnt(0)" ::: "memory");
    __builtin_amdgcn_sched_barrier(0);
    __builtin_amdgcn_s_setprio(1);
#pragma unroll
    for (int nf = 2; nf < 4; ++nf)
#pragma unroll
      for (int mf = 0; mf < 8; ++mf)
        acc[mf][nf] = __builtin_amdgcn_mfma_f32_16x16x32_bf16(a[mf], b[nf], acc[mf][nf], 0, 0, 0);
    __builtin_amdgcn_s_setprio(0);
    __builtin_amdgcn_s_barrier();
  }

  // Epilogue: C/D layout col=lane&15, row=(lane>>4)*4+reg (m89-verified)
#pragma unroll
  for (int mf = 0; mf < 8; ++mf) {
#pragma unroll
    for (int nf = 0; nf < 4; ++nf) {
      int mrow = m0 + wr * 128 + mf * 16 + lg * 4;
      int ncol = n0 + wc * 64 + nf * 16 + lr;
#pragma unroll
      for (int r = 0; r < 4; ++r) {
        if constexpr (sizeof(OT) == 2)
          C[(size_t)(mrow + r) * N + ncol] = (OT)f2bf(acc[mf][nf][r]);
        else
          C[(size_t)(mrow + r) * N + ncol] = (OT)acc[mf][nf][r];
      }
    }
  }
}

// ---------------- conv(4, causal, depthwise) + silu (bf16 in/out) ---------
__global__ void conv_silu_kernel(const unsigned short* __restrict__ xzb,
                                 const float* __restrict__ conv_w,
                                 const float* __restrict__ conv_b,
                                 unsigned short* __restrict__ xc_bf) {
  int i4 = blockIdx.x * 256 + threadIdx.x;   // over 2048*1024 groups of 4
  int e4 = i4 & 1023;
  int m = i4 >> 10;
  int l = m & 1023;
  float4 cw0 = reinterpret_cast<const float4*>(conv_w)[e4 * 4 + 0];
  float4 cw1 = reinterpret_cast<const float4*>(conv_w)[e4 * 4 + 1];
  float4 cw2 = reinterpret_cast<const float4*>(conv_w)[e4 * 4 + 2];
  float4 cw3 = reinterpret_cast<const float4*>(conv_w)[e4 * 4 + 3];
  float4 acc = reinterpret_cast<const float4*>(conv_b)[e4];
#pragma unroll
  for (int k = 0; k < 4; ++k) {
    if (l - 3 + k >= 0) {
      ushort4 xv = reinterpret_cast<const ushort4*>(xzb)[(size_t)(m - 3 + k) * 2048 + e4];
      acc.x = fmaf(bf2f(xv.x), ((const float*)&cw0)[k], acc.x);
      acc.y = fmaf(bf2f(xv.y), ((const float*)&cw1)[k], acc.y);
      acc.z = fmaf(bf2f(xv.z), ((const float*)&cw2)[k], acc.z);
      acc.w = fmaf(bf2f(xv.w), ((const float*)&cw3)[k], acc.w);
    }
  }
  ushort4 o;
  o.x = f2bf(silu_f(acc.x)); o.y = f2bf(silu_f(acc.y));
  o.z = f2bf(silu_f(acc.z)); o.w = f2bf(silu_f(acc.w));
  reinterpret_cast<ushort4*>(xc_bf)[i4] = o;
}

// ---------------- SSM scan: chunked 2-pass ----------------
__device__ __forceinline__ void dA_powers(float r, float* dA) {
  float r2 = r * r, r4 = r2 * r2, r8 = r4 * r4;
  dA[0] = r;        dA[1] = r2;       dA[2] = r2 * r;   dA[3] = r4;
  dA[4] = r4 * r;   dA[5] = r4 * r2;  dA[6] = dA[5] * r; dA[7] = r8;
  dA[8] = r8 * r;   dA[9] = r8 * r2;  dA[10] = dA[9] * r; dA[11] = r8 * r4;
  dA[12] = dA[11] * r; dA[13] = dA[11] * r2; dA[14] = dA[13] * r; dA[15] = r8 * r8;
}

__global__ __launch_bounds__(256)
void scan_pass1(const float* __restrict__ delta, const float* __restrict__ dbc,
                const unsigned short* __restrict__ xcb, const float* __restrict__ A_log,
                float* __restrict__ hfin, float* __restrict__ Pprod) {
  __shared__ float Bsh[1024];           // [64][16]
  const int tid = threadIdx.x;
  const int bc = blockIdx.x >> 4;       // b*16 + c
  const int eg = blockIdx.x & 15;
  const int b = bc >> 4, c = bc & 15;
  const int e = eg * 256 + tid;
  const int mb = b * 1024 + c * 64;
  for (int i = tid; i < 1024; i += 256)
    Bsh[i] = dbc[(size_t)(mb + (i >> 4)) * 256 + 128 + (i & 15)];
  __syncthreads();

  float A[16];
  const float4* al = reinterpret_cast<const float4*>(A_log + (size_t)e * 16);
#pragma unroll
  for (int q = 0; q < 4; ++q) {
    float4 v = al[q];
    A[q * 4 + 0] = -__expf(v.x); A[q * 4 + 1] = -__expf(v.y);
    A[q * 4 + 2] = -__expf(v.z); A[q * 4 + 3] = -__expf(v.w);
  }
  bool fastp = true;
#pragma unroll
  for (int s = 0; s < 16; ++s)
    fastp = fastp && (fabsf(A[s] + (float)(s + 1)) <= 1e-5f * (float)(s + 1));

  float h[16], P[16];
#pragma unroll
  for (int s = 0; s < 16; ++s) { h[s] = 0.f; P[s] = 1.f; }

  if (fastp) {
    float sd = 0.f;
    for (int ll = 0; ll < 64; ++ll) {
      const size_t m = (size_t)(mb + ll);
      float dl = delta[m * 4096 + e];
      float dxc = dl * bf2f(xcb[m * 4096 + e]);
      sd += dl;
      float dA[16];
      dA_powers(__expf(-dl), dA);
#pragma unroll
      for (int s = 0; s < 16; ++s)
        h[s] = fmaf(dA[s], h[s], Bsh[ll * 16 + s] * dxc);
    }
    dA_powers(__expf(-sd), P);   // P[s] = exp(-sum_delta)^(s+1)
  } else {
    for (int ll = 0; ll < 64; ++ll) {
      const size_t m = (size_t)(mb + ll);
      float dl = delta[m * 4096 + e];
      float dxc = dl * bf2f(xcb[m * 4096 + e]);
#pragma unroll
      for (int s = 0; s < 16; ++s) {
        float dA = __expf(dl * A[s]);
        P[s] *= dA;
        h[s] = fmaf(dA, h[s], Bsh[ll * 16 + s] * dxc);
      }
    }
  }
  float* hp = hfin + ((size_t)bc * 4096 + e) * 16;
  float* pp = Pprod + ((size_t)bc * 4096 + e) * 16;
#pragma unroll
  for (int s = 0; s < 16; ++s) { hp[s] = h[s]; pp[s] = P[s]; }
}

__global__ void scan_pass2(float* __restrict__ hfin, const float* __restrict__ Pprod) {
  int idx = blockIdx.x * 256 + threadIdx.x;   // 2*4096*16 = 131072
  int b = idx >> 16;
  int es = idx & 65535;                       // e*16 + s
  float H = 0.f;
  for (int c = 0; c < 16; ++c) {
    size_t o = ((size_t)(b * 16 + c) << 16) + es;
    float hf = hfin[o];
    float Pp = Pprod[o];
    hfin[o] = H;                              // carry-in for chunk c
    H = fmaf(Pp, H, hf);
  }
}

__global__ __launch_bounds__(256)
void scan_pass3(const float* __restrict__ delta, const float* __restrict__ dbc,
                const unsigned short* __restrict__ xcb, const unsigned short* __restrict__ xzb,
                const float* __restrict__ A_log, const float* __restrict__ Dp,
                const float* __restrict__ hcarry, unsigned short* __restrict__ y_bf) {
  __shared__ float Bsh[1024];           // [64][16]
  __shared__ float Csh[1024];
  const int tid = threadIdx.x;
  const int bc = blockIdx.x >> 4;
  const int eg = blockIdx.x & 15;
  const int b = bc >> 4, c = bc & 15;
  const int e = eg * 256 + tid;
  const int mb = b * 1024 + c * 64;
  for (int i = tid; i < 1024; i += 256) {
    size_t base = (size_t)(mb + (i >> 4)) * 256 + (i & 15);
    Bsh[i] = dbc[base + 128];
    Csh[i] = dbc[base + 144];
  }
  __syncthreads();

  float A[16];
  const float4* al = reinterpret_cast<const float4*>(A_log + (size_t)e * 16);
#pragma unroll
  for (int q = 0; q < 4; ++q) {
    float4 v = al[q];
    A[q * 4 + 0] = -__expf(v.x); A[q * 4 + 1] = -__expf(v.y);
    A[q * 4 + 2] = -__expf(v.z); A[q * 4 + 3] = -__expf(v.w);
  }
  bool fastp = true;
#pragma unroll
  for (int s = 0; s < 16; ++s)
    fastp = fastp && (fabsf(A[s] + (float)(s + 1)) <= 1e-5f * (float)(s + 1));

  float h[16];
  const float* hp = hcarry + ((size_t)bc * 4096 + e) * 16;
#pragma unroll
  for (int s = 0; s < 16; ++s) h[s] = hp[s];
  const float Dv = Dp[e];

  if (fastp) {
    for (int ll = 0; ll < 64; ++ll) {
      const size_t m = (size_t)(mb + ll);
      float dl = delta[m * 4096 + e];
      float xcv = bf2f(xcb[m * 4096 + e]);
      float dxc = dl * xcv;
      float dA[16];
      dA_powers(__expf(-dl), dA);
      float y = 0.f;
#pragma unroll
      for (int s = 0; s < 16; ++s) {
        h[s] = fmaf(dA[s], h[s], Bsh[ll * 16 + s] * dxc);
        y = fmaf(h[s], Csh[ll * 16 + s], y);
      }
      float z = bf2f(xzb[m * 8192 + 4096 + e]);
      y = (y + xcv * Dv) * silu_f(z);
      y_bf[m * 4096 + e] = f2bf(y);
    }
  } else {
    for (int ll = 0; ll < 64; ++ll) {
      const size_t m = (size_t)(mb + ll);
      float dl = delta[m * 4096 + e];
      float xcv = bf2f(xcb[m * 4096 + e]);
      float dxc = dl * xcv;
      float y = 0.f;
#pragma unroll
      for (int s = 0; s < 16; ++s) {
        float dA = __expf(dl * A[s]);
        h[s] = fmaf(dA, h[s], Bsh[ll * 16 + s] * dxc);
        y = fmaf(h[s], Csh[ll * 16 + s], y);
      }
      float z = bf2f(xzb[m * 8192 + 4096 + e]);
      y = (y + xcv * Dv) * silu_f(z);
      y_bf[m * 4096 + e] = f2bf(y);
    }
  }
}

// ---------------------------------------------------------------------------
extern "C" void kernel_launch(void* const* d_in, const int* in_sizes, int n_in,
                              void* d_out, int out_size, void* d_ws, size_t ws_size,
                              hipStream_t stream) {
  const float* x      = (const float*)d_in[0];
  const float* W_in   = (const float*)d_in[1];
  const float* conv_w = (const float*)d_in[2];
  const float* conv_b = (const float*)d_in[3];
  const float* W_x    = (const float*)d_in[4];
  const float* W_dt   = (const float*)d_in[5];
  const float* b_dt   = (const float*)d_in[6];
  const float* A_log  = (const float*)d_in[7];
  const float* Dp     = (const float*)d_in[8];
  const float* W_out  = (const float*)d_in[9];
  float* out = (float*)d_out;
  char* ws = (char*)d_ws;

  // workspace (190,316,544 B; time-disjoint aliases):
  // slot0 (+0, 33.5 MB): Win_bf -> gpart2 -> delta (fp32)
  // +33554432 (16.8 MB): x_bf -> y_bf
  // +50331648 (16.8 MB): Wout_bf | +67108864 Wx_bf | +69206016 Wdt_bf
  // +70254592 (33.5 MB): xz_bf (bf16 [2048][8192])
  // +103809024 (67.1 MB): hfin/Pprod (scan-time) -> gpart4 bf16 x8 planes
  //   (67.1 MB, after pass3; time-disjoint)
  // +170917888 (16.8 MB): xc_bf | +187695104 dbc | +189792256 dt_bf
  unsigned short* Win_bf    = (unsigned short*)(ws + 0);
  float*          gpart2    = (float*)(ws + 0);
  float*          delta     = (float*)(ws + 0);
  unsigned short* x_bf      = (unsigned short*)(ws + 33554432);
  unsigned short* y_bf      = (unsigned short*)(ws + 33554432);   // alias (after GEMM1)
  unsigned short* Wout_bf   = (unsigned short*)(ws + 50331648);
  unsigned short* Wx_bf     = (unsigned short*)(ws + 67108864);
  unsigned short* Wdt_bf    = (unsigned short*)(ws + 69206016);
  unsigned short* xz_bf     = (unsigned short*)(ws + 70254592);
  unsigned short* gpart4    = (unsigned short*)(ws + 103809024);  // alias (after pass3)
  float*          hfin      = (float*)(ws + 103809024);           // scan-time
  float*          Pprod     = (float*)(ws + 145752064);
  unsigned short* xc_bf     = (unsigned short*)(ws + 170917888);
  float*          dbc       = (float*)(ws + 187695104);
  unsigned short* dt_bf     = (unsigned short*)(ws + 189792256);

  // fused casts (x, W_in, W_out, W_dt, Wx-pad)
  cast_all<<<30208, 256, 0, stream>>>(x, W_in, W_out, W_dt, W_x,
                                      x_bf, Win_bf, Wout_bf, Wdt_bf, Wx_bf);

  // GEMM1: xz_bf[2048][8192] = x @ W_in^T (bf16 output)
  gemm_bt_8ph<unsigned short><<<256, 512, 0, stream>>>(x_bf, Win_bf, xz_bf, 2048, 8192, 2048, 8, 2048);

  // conv + silu -> xc_bf
  conv_silu_kernel<<<8192, 256, 0, stream>>>(xz_bf, conv_w, conv_b, xc_bf);

  // GEMM2 (split-K=8): partials[8][2048][256] = xc @ Wx_pad^T
  gemm_bt<<<dim3(2, 16, 8), 256, 0, stream>>>(xc_bf, Wx_bf, gpart2, 2048, 256, 4096, 512, nullptr);
  reduce8_dbc<<<2048, 256, 0, stream>>>(gpart2, dbc, dt_bf);

  // GEMM3 (+fused bias+softplus): delta[2048][4096] = sp(dt @ W_dt^T + b_dt)
  gemm_bt<<<dim3(32, 16, 1), 256, 0, stream>>>(dt_bf, Wdt_bf, delta, 2048, 4096, 128, 128, b_dt);

  // SSM scan: chunked two-pass
  scan_pass1<<<512, 256, 0, stream>>>(delta, dbc, xc_bf, A_log, hfin, Pprod);
  scan_pass2<<<512, 256, 0, stream>>>(hfin, Pprod);
  scan_pass3<<<512, 256, 0, stream>>>(delta, dbc, xc_bf, xz_bf, A_log, Dp, hfin, y_bf);

  // GEMM4 (2ph 64KB, split-K=8, bf16 partials): 512 blocks = 2/CU
  gemm_bt_2ph<unsigned short><<<dim3(64, 1, 8), 512, 0, stream>>>(y_bf, Wout_bf, gpart4, 2048, 2048, 4096, 8, 512);
  reduce8_out_bf<<<4096, 256, 0, stream>>>(gpart4, out);
}

// Round 16
// 321.564 us; speedup vs baseline: 1.9172x; 1.9172x over previous
//
#include <hip/hip_runtime.h>
#include <cstdint>

// ---------------------------------------------------------------------------
// Mamba block. GEMM1/GEMM4: 256^2 tile 8-wave m201-style pipelined kernel
// (T2+T3+T4+T5, R9 schedule); GEMM1 writes bf16 xz, GEMM4 split-K=4 with
// bf16 partials (+reduce4_bf). GEMM2: m97 split-K=8 (+fused reduce->dbc,
// dt_bf). GEMM3: m97 +bias/softplus, fp32 delta. Scan: chunked 2-pass, bf16
// xc/z, fast dA path (r-powers; P from sum-delta) with generic fallback.
// NOTE (R15 lesson): do NOT raise min-waves on the 8-wave 256^2 tile --
// launch_bounds(512,4) caps VGPR at 128 < ~200 needed -> acc spills to
// scratch (observed: 924 MB scratch writes, MfmaUtil 0.3%, 2x slowdown).
// ---------------------------------------------------------------------------

typedef __bf16 bf16x8 __attribute__((ext_vector_type(8)));
typedef float f32x4 __attribute__((ext_vector_type(4)));

__device__ __forceinline__ unsigned short f2bf(float f) {
  uint32_t u = __float_as_uint(f);
  u += 0x7FFFu + ((u >> 16) & 1u);   // round-to-nearest-even
  return (unsigned short)(u >> 16);
}

__device__ __forceinline__ float bf2f(unsigned short v) {
  return __uint_as_float(((uint32_t)v) << 16);
}

__device__ __forceinline__ float silu_f(float v) {
  return v / (1.f + __expf(-v));
}

__device__ __forceinline__ float softplus_f(float v) {
  return (v > 20.f) ? v : log1pf(__expf(v));
}

// ---------------- fused cast kernel (all bf16 operand prep) ----------------
__global__ void cast_all(const float* __restrict__ x, const float* __restrict__ W_in,
                         const float* __restrict__ W_out, const float* __restrict__ W_dt,
                         const float* __restrict__ W_x,
                         unsigned short* __restrict__ x_bf, unsigned short* __restrict__ Win_bf,
                         unsigned short* __restrict__ Wout_bf, unsigned short* __restrict__ Wdt_bf,
                         unsigned short* __restrict__ Wx_bf) {
  int i = blockIdx.x * 256 + threadIdx.x;   // over 7,733,248 float4 groups
  const float4* s4; ushort4* d4; int j;
  if (i < 1048576)      { s4 = (const float4*)x;     d4 = (ushort4*)x_bf;    j = i; }
  else if (i < 5242880) { s4 = (const float4*)W_in;  d4 = (ushort4*)Win_bf;  j = i - 1048576; }
  else if (i < 7340032) { s4 = (const float4*)W_out; d4 = (ushort4*)Wout_bf; j = i - 5242880; }
  else if (i < 7471104) { s4 = (const float4*)W_dt;  d4 = (ushort4*)Wdt_bf;  j = i - 7340032; }
  else {
    j = i - 7471104;
    ushort4 o = {0, 0, 0, 0};
    if (j < 163840) {   // 160*4096/4
      float4 v = ((const float4*)W_x)[j];
      o.x = f2bf(v.x); o.y = f2bf(v.y); o.z = f2bf(v.z); o.w = f2bf(v.w);
    }
    ((ushort4*)Wx_bf)[j] = o;
    return;
  }
  float4 v = s4[j];
  ushort4 o; o.x = f2bf(v.x); o.y = f2bf(v.y); o.z = f2bf(v.z); o.w = f2bf(v.w);
  d4[j] = o;
}

// ---------------- m97-style bf16 MFMA GEMM (128^2, BK=32, split-K) --------
#define BM 128
#define BN 128
#define BKK 32

__device__ __forceinline__ void stage_tile(const unsigned short* __restrict__ G,
                                           int ldK, int g0, int k0,
                                           unsigned short* lds, int wave, int lane) {
#pragma unroll
  for (int c = 0; c < 2; ++c) {
    int row = c * 64 + wave * 16 + (lane >> 2);
    int col = (lane & 3) * 8;
    const unsigned short* src = G + (size_t)(g0 + row) * ldK + (k0 + col);
    unsigned short* dst = lds + c * 2048 + wave * 512;  // ushort units
    __builtin_amdgcn_global_load_lds((__attribute__((address_space(1))) void*)(src),
                                     (__attribute__((address_space(3))) void*)(dst),
                                     16, 0, 0);
  }
}

__global__ __launch_bounds__(256)
void gemm_bt(const unsigned short* __restrict__ A, const unsigned short* __restrict__ B,
             float* __restrict__ C, int M, int N, int ldK, int kchunk,
             const float* __restrict__ bias_sp) {
  __shared__ unsigned short As[BM * BKK];
  __shared__ unsigned short Bs[BN * BKK];
  const int tid = threadIdx.x;
  const int wave = tid >> 6, lane = tid & 63;
  const int wr = wave >> 1, wc = wave & 1;
  const int m0 = blockIdx.y * BM, n0 = blockIdx.x * BN;
  const int lr = lane & 15, lg = lane >> 4;
  const int kb = blockIdx.z * kchunk, ke = kb + kchunk;
  C += (size_t)blockIdx.z * M * N;

  f32x4 zero = {0.f, 0.f, 0.f, 0.f};
  f32x4 acc[4][4];
#pragma unroll
  for (int i = 0; i < 4; ++i)
#pragma unroll
    for (int j = 0; j < 4; ++j) acc[i][j] = zero;

  for (int k0 = kb; k0 < ke; k0 += BKK) {
    stage_tile(A, ldK, m0, k0, As, wave, lane);
    stage_tile(B, ldK, n0, k0, Bs, wave, lane);
    __syncthreads();
    bf16x8 af[4], bfr[4];
#pragma unroll
    for (int i = 0; i < 4; ++i)
      af[i] = *reinterpret_cast<const bf16x8*>(&As[(wr * 64 + i * 16 + lr) * BKK + lg * 8]);
#pragma unroll
    for (int j = 0; j < 4; ++j)
      bfr[j] = *reinterpret_cast<const bf16x8*>(&Bs[(wc * 64 + j * 16 + lr) * BKK + lg * 8]);
#pragma unroll
    for (int i = 0; i < 4; ++i)
#pragma unroll
      for (int j = 0; j < 4; ++j)
        acc[i][j] = __builtin_amdgcn_mfma_f32_16x16x32_bf16(af[i], bfr[j], acc[i][j], 0, 0, 0);
    __syncthreads();
  }

#pragma unroll
  for (int i = 0; i < 4; ++i) {
#pragma unroll
    for (int j = 0; j < 4; ++j) {
      int mrow = m0 + wr * 64 + i * 16 + lg * 4;
      int ncol = n0 + wc * 64 + j * 16 + lr;
      if (bias_sp) {
        float bv = bias_sp[ncol];
#pragma unroll
        for (int r = 0; r < 4; ++r)
          C[(size_t)(mrow + r) * N + ncol] = softplus_f(acc[i][j][r] + bv);
      } else {
#pragma unroll
        for (int r = 0; r < 4; ++r)
          C[(size_t)(mrow + r) * N + ncol] = acc[i][j][r];
      }
    }
  }
}

// split-K reducers --------------------------------------------------------
__global__ void reduce8_dbc(const float* __restrict__ p, float* __restrict__ dbc,
                            unsigned short* __restrict__ dt_bf) {
  int i = blockIdx.x * 256 + threadIdx.x;   // over 524288
  float s = 0.f;
#pragma unroll
  for (int c = 0; c < 8; ++c) s += p[(size_t)c * 524288 + i];
  dbc[i] = s;
  int col = i & 255;
  if (col < 128) dt_bf[(size_t)(i >> 8) * 128 + col] = f2bf(s);
}

// GEMM4: out = sum of 4 bf16 partial planes of [2048][2048].
__global__ void reduce4_out_bf(const unsigned short* __restrict__ p, float* __restrict__ out) {
  int i = blockIdx.x * 256 + threadIdx.x;   // over 1048576 ushort4 groups
  const ushort4* p4 = reinterpret_cast<const ushort4*>(p);
  ushort4 a = p4[i], b = p4[i + 1048576], c = p4[i + 2097152], d = p4[i + 3145728];
  float4 r;
  r.x = (bf2f(a.x) + bf2f(b.x)) + (bf2f(c.x) + bf2f(d.x));
  r.y = (bf2f(a.y) + bf2f(b.y)) + (bf2f(c.y) + bf2f(d.y));
  r.z = (bf2f(a.z) + bf2f(b.z)) + (bf2f(c.z) + bf2f(d.z));
  r.w = (bf2f(a.w) + bf2f(b.w)) + (bf2f(c.w) + bf2f(d.w));
  reinterpret_cast<float4*>(out)[i] = r;
}

// ---------------- 256^2-tile m201-faithful pipelined GEMM (+split-K) -------
// R9 schedule (verified 76.5us GEMM1 / 324us total): per tile t, 4 phases
//   ph0: reads a[0..7]k0,b01k0 (10); stage q0(t+1); vmcnt(6)
//   ph1: reads b23k0 (2);            stage q1(t+1); vmcnt(4)
//   ph2: reads a[0..7]k1,b01k1 (10); stage q2(t+1); (no wait)
//   ph3: reads b23k1 (2);            stage q3(t+1); vmcnt(4)
// each phase: ... -> bar -> lgkm0+schedbar -> setprio/16 MFMA -> bar.
// vmcnt never 0 mid-loop; buffer refilled only >=2 barriers after its last
// reader. T2 both-sides swizzle (rule #21). M,N %256==0, kchunk%64==0.
template <typename OT>
__global__ __launch_bounds__(512, 2)
void gemm_bt_8ph(const unsigned short* __restrict__ A,
                 const unsigned short* __restrict__ B,
                 OT* __restrict__ C, int M, int N, int K, int nbm, int kchunk) {
  __shared__ unsigned short As[2][16384];   // [buf][ks*8192 + row*32 + col]
  __shared__ unsigned short Bs[2][16384];
  const int tid = threadIdx.x;
  const int wid = tid >> 6, lane = tid & 63;
  const int wr = wid >> 2, wc = wid & 3;     // 2 x 4 waves
  const int lr = lane & 15, lg = lane >> 4;

  const int cpx = gridDim.x >> 3;
  const int x = blockIdx.x;
  const int wg = (x & 7) * cpx + (x >> 3);
  const int bm = wg % nbm, bn = wg / nbm;
  const int m0 = bm * 256, n0 = bn * 256;
  const int kb = blockIdx.z * kchunk;
  C += (size_t)blockIdx.z * M * N;

  f32x4 acc[8][4];
  f32x4 zero = {0.f, 0.f, 0.f, 0.f};
#pragma unroll
  for (int i = 0; i < 8; ++i)
#pragma unroll
    for (int j = 0; j < 4; ++j) acc[i][j] = zero;

  const int nt = kchunk / 64;

  // q: 0 = A ks0, 1 = B ks0, 2 = A ks1, 3 = B ks1. Half = 256 rows x 32 cols.
  auto QUANT = [&](int t, int q) {
    const int buf = t & 1;
    const int ks = q >> 1;
    const unsigned short* G = (q & 1) ? B : A;
    const int g0 = (q & 1) ? n0 : m0;
    unsigned short* lds = ((q & 1) ? &Bs[buf][0] : &As[buf][0]) + ks * 8192;
    const int k0 = kb + t * 64 + ks * 32;
#pragma unroll
    for (int r = 0; r < 2; ++r) {
      int row = r * 128 + (tid >> 2);
      int scol = ((tid & 3) * 8) ^ (((row >> 1) & 3) << 3);
      const unsigned short* src = G + (size_t)(g0 + row) * K + (k0 + scol);
      __builtin_amdgcn_global_load_lds(
          (__attribute__((address_space(1))) const void*)(src),
          (__attribute__((address_space(3))) void*)(lds + r * 4096 + tid * 8),
          16, 0, 0);
    }
  };

  auto RD_A = [&](int buf, int ks, int mf) -> bf16x8 {
    int row = wr * 128 + mf * 16 + lr;
    int col = (lg * 8) ^ (((row >> 1) & 3) << 3);
    return *reinterpret_cast<const bf16x8*>(&As[buf][ks * 8192 + row * 32 + col]);
  };
  auto RD_B = [&](int buf, int ks, int nf) -> bf16x8 {
    int row = wc * 64 + nf * 16 + lr;
    int col = (lg * 8) ^ (((row >> 1) & 3) << 3);
    return *reinterpret_cast<const bf16x8*>(&Bs[buf][ks * 8192 + row * 32 + col]);
  };

  // prologue: all 4 halves of tile 0; ensure q0,q1 landed (q2,q3 may fly)
  QUANT(0, 0); QUANT(0, 1); QUANT(0, 2); QUANT(0, 3);
  asm volatile("s_waitcnt vmcnt(4)" ::: "memory");
  __builtin_amdgcn_s_barrier();

  bf16x8 a[8], b[4];
  for (int t = 0; t < nt; ++t) {
    const int buf = t & 1;
    const bool pf = (t + 1 < nt);
    // ---------------- ph0 (ks0, nf 0-1) ----------------
#pragma unroll
    for (int mf = 0; mf < 8; ++mf) a[mf] = RD_A(buf, 0, mf);
    b[0] = RD_B(buf, 0, 0); b[1] = RD_B(buf, 0, 1);
    if (pf) {
      QUANT(t + 1, 0);
      asm volatile("s_waitcnt vmcnt(6)" ::: "memory");
    } else {
      asm volatile("s_waitcnt vmcnt(4)" ::: "memory");
    }
    __builtin_amdgcn_s_barrier();
    asm volatile("s_waitcnt lgkmcnt(0)" ::: "memory");
    __builtin_amdgcn_sched_barrier(0);
    __builtin_amdgcn_s_setprio(1);
#pragma unroll
    for (int nf = 0; nf < 2; ++nf)
#pragma unroll
      for (int mf = 0; mf < 8; ++mf)
        acc[mf][nf] = __builtin_amdgcn_mfma_f32_16x16x32_bf16(a[mf], b[nf], acc[mf][nf], 0, 0, 0);
    __builtin_amdgcn_s_setprio(0);
    __builtin_amdgcn_s_barrier();
    // ---------------- ph1 (ks0, nf 2-3) ----------------
    b[2] = RD_B(buf, 0, 2); b[3] = RD_B(buf, 0, 3);
    if (pf) {
      QUANT(t + 1, 1);
      asm volatile("s_waitcnt vmcnt(4)" ::: "memory");
    } else {
      asm volatile("s_waitcnt vmcnt(0)" ::: "memory");
    }
    __builtin_amdgcn_s_barrier();
    asm volatile("s_waitcnt lgkmcnt(0)" ::: "memory");
    __builtin_amdgcn_sched_barrier(0);
    __builtin_amdgcn_s_setprio(1);
#pragma unroll
    for (int nf = 2; nf < 4; ++nf)
#pragma unroll
      for (int mf = 0; mf < 8; ++mf)
        acc[mf][nf] = __builtin_amdgcn_mfma_f32_16x16x32_bf16(a[mf], b[nf], acc[mf][nf], 0, 0, 0);
    __builtin_amdgcn_s_setprio(0);
    __builtin_amdgcn_s_barrier();
    // ---------------- ph2 (ks1, nf 0-1) ----------------
#pragma unroll
    for (int mf = 0; mf < 8; ++mf) a[mf] = RD_A(buf, 1, mf);
    b[0] = RD_B(buf, 1, 0); b[1] = RD_B(buf, 1, 1);
    if (pf) QUANT(t + 1, 2);
    __builtin_amdgcn_s_barrier();
    asm volatile("s_waitcnt lgkmcnt(0)" ::: "memory");
    __builtin_amdgcn_sched_barrier(0);
    __builtin_amdgcn_s_setprio(1);
#pragma unroll
    for (int nf = 0; nf < 2; ++nf)
#pragma unroll
      for (int mf = 0; mf < 8; ++mf)
        acc[mf][nf] = __builtin_amdgcn_mfma_f32_16x16x32_bf16(a[mf], b[nf], acc[mf][nf], 0, 0, 0);
    __builtin_amdgcn_s_setprio(0);
    __builtin_amdgcn_s_barrier();
    // ---------------- ph3 (ks1, nf 2-3) ----------------
    b[2] = RD_B(buf, 1, 2); b[3] = RD_B(buf, 1, 3);
    if (pf) {
      QUANT(t + 1, 3);
      asm volatile("s_waitcnt vmcnt(4)" ::: "memory");
    }
    __builtin_amdgcn_s_barrier();
    asm volatile("s_waitcnt lgkmcnt(0)" ::: "memory");
    __builtin_amdgcn_sched_barrier(0);
    __builtin_amdgcn_s_setprio(1);
#pragma unroll
    for (int nf = 2; nf < 4; ++nf)
#pragma unroll
      for (int mf = 0; mf < 8; ++mf)
        acc[mf][nf] = __builtin_amdgcn_mfma_f32_16x16x32_bf16(a[mf], b[nf], acc[mf][nf], 0, 0, 0);
    __builtin_amdgcn_s_setprio(0);
    __builtin_amdgcn_s_barrier();
  }

  // Epilogue: C/D layout col=lane&15, row=(lane>>4)*4+reg (m89-verified)
#pragma unroll
  for (int mf = 0; mf < 8; ++mf) {
#pragma unroll
    for (int nf = 0; nf < 4; ++nf) {
      int mrow = m0 + wr * 128 + mf * 16 + lg * 4;
      int ncol = n0 + wc * 64 + nf * 16 + lr;
#pragma unroll
      for (int r = 0; r < 4; ++r) {
        if constexpr (sizeof(OT) == 2)
          C[(size_t)(mrow + r) * N + ncol] = (OT)f2bf(acc[mf][nf][r]);
        else
          C[(size_t)(mrow + r) * N + ncol] = (OT)acc[mf][nf][r];
      }
    }
  }
}

// ---------------- conv(4, causal, depthwise) + silu (bf16 in/out) ---------
__global__ void conv_silu_kernel(const unsigned short* __restrict__ xzb,
                                 const float* __restrict__ conv_w,
                                 const float* __restrict__ conv_b,
                                 unsigned short* __restrict__ xc_bf) {
  int i4 = blockIdx.x * 256 + threadIdx.x;   // over 2048*1024 groups of 4
  int e4 = i4 & 1023;
  int m = i4 >> 10;
  int l = m & 1023;
  float4 cw0 = reinterpret_cast<const float4*>(conv_w)[e4 * 4 + 0];
  float4 cw1 = reinterpret_cast<const float4*>(conv_w)[e4 * 4 + 1];
  float4 cw2 = reinterpret_cast<const float4*>(conv_w)[e4 * 4 + 2];
  float4 cw3 = reinterpret_cast<const float4*>(conv_w)[e4 * 4 + 3];
  float4 acc = reinterpret_cast<const float4*>(conv_b)[e4];
#pragma unroll
  for (int k = 0; k < 4; ++k) {
    if (l - 3 + k >= 0) {
      ushort4 xv = reinterpret_cast<const ushort4*>(xzb)[(size_t)(m - 3 + k) * 2048 + e4];
      acc.x = fmaf(bf2f(xv.x), ((const float*)&cw0)[k], acc.x);
      acc.y = fmaf(bf2f(xv.y), ((const float*)&cw1)[k], acc.y);
      acc.z = fmaf(bf2f(xv.z), ((const float*)&cw2)[k], acc.z);
      acc.w = fmaf(bf2f(xv.w), ((const float*)&cw3)[k], acc.w);
    }
  }
  ushort4 o;
  o.x = f2bf(silu_f(acc.x)); o.y = f2bf(silu_f(acc.y));
  o.z = f2bf(silu_f(acc.z)); o.w = f2bf(silu_f(acc.w));
  reinterpret_cast<ushort4*>(xc_bf)[i4] = o;
}

// ---------------- SSM scan: chunked 2-pass ----------------
// dA fast path: if A[s] == -(s+1) (true here: A_log = log(1..16)),
// dA[s] = r^(s+1), r = exp(-delta); P[s] = exp(-sum_delta)^(s+1) once per
// chunk. Generic fallback otherwise (uniform branch).
__device__ __forceinline__ void dA_powers(float r, float* dA) {
  float r2 = r * r, r4 = r2 * r2, r8 = r4 * r4;
  dA[0] = r;        dA[1] = r2;       dA[2] = r2 * r;   dA[3] = r4;
  dA[4] = r4 * r;   dA[5] = r4 * r2;  dA[6] = dA[5] * r; dA[7] = r8;
  dA[8] = r8 * r;   dA[9] = r8 * r2;  dA[10] = dA[9] * r; dA[11] = r8 * r4;
  dA[12] = dA[11] * r; dA[13] = dA[11] * r2; dA[14] = dA[13] * r; dA[15] = r8 * r8;
}

__global__ __launch_bounds__(256)
void scan_pass1(const float* __restrict__ delta, const float* __restrict__ dbc,
                const unsigned short* __restrict__ xcb, const float* __restrict__ A_log,
                float* __restrict__ hfin, float* __restrict__ Pprod) {
  __shared__ float Bsh[1024];           // [64][16]
  const int tid = threadIdx.x;
  const int bc = blockIdx.x >> 4;       // b*16 + c
  const int eg = blockIdx.x & 15;
  const int b = bc >> 4, c = bc & 15;
  const int e = eg * 256 + tid;
  const int mb = b * 1024 + c * 64;
  for (int i = tid; i < 1024; i += 256)
    Bsh[i] = dbc[(size_t)(mb + (i >> 4)) * 256 + 128 + (i & 15)];
  __syncthreads();

  float A[16];
  const float4* al = reinterpret_cast<const float4*>(A_log + (size_t)e * 16);
#pragma unroll
  for (int q = 0; q < 4; ++q) {
    float4 v = al[q];
    A[q * 4 + 0] = -__expf(v.x); A[q * 4 + 1] = -__expf(v.y);
    A[q * 4 + 2] = -__expf(v.z); A[q * 4 + 3] = -__expf(v.w);
  }
  bool fastp = true;
#pragma unroll
  for (int s = 0; s < 16; ++s)
    fastp = fastp && (fabsf(A[s] + (float)(s + 1)) <= 1e-5f * (float)(s + 1));

  float h[16], P[16];
#pragma unroll
  for (int s = 0; s < 16; ++s) { h[s] = 0.f; P[s] = 1.f; }

  if (fastp) {
    float sd = 0.f;
    for (int ll = 0; ll < 64; ++ll) {
      const size_t m = (size_t)(mb + ll);
      float dl = delta[m * 4096 + e];
      float dxc = dl * bf2f(xcb[m * 4096 + e]);
      sd += dl;
      float dA[16];
      dA_powers(__expf(-dl), dA);
#pragma unroll
      for (int s = 0; s < 16; ++s)
        h[s] = fmaf(dA[s], h[s], Bsh[ll * 16 + s] * dxc);
    }
    dA_powers(__expf(-sd), P);   // P[s] = exp(-sum_delta)^(s+1)
  } else {
    for (int ll = 0; ll < 64; ++ll) {
      const size_t m = (size_t)(mb + ll);
      float dl = delta[m * 4096 + e];
      float dxc = dl * bf2f(xcb[m * 4096 + e]);
#pragma unroll
      for (int s = 0; s < 16; ++s) {
        float dA = __expf(dl * A[s]);
        P[s] *= dA;
        h[s] = fmaf(dA, h[s], Bsh[ll * 16 + s] * dxc);
      }
    }
  }
  float* hp = hfin + ((size_t)bc * 4096 + e) * 16;
  float* pp = Pprod + ((size_t)bc * 4096 + e) * 16;
#pragma unroll
  for (int s = 0; s < 16; ++s) { hp[s] = h[s]; pp[s] = P[s]; }
}

__global__ void scan_pass2(float* __restrict__ hfin, const float* __restrict__ Pprod) {
  int idx = blockIdx.x * 256 + threadIdx.x;   // 2*4096*16 = 131072
  int b = idx >> 16;
  int es = idx & 65535;                       // e*16 + s
  float H = 0.f;
  for (int c = 0; c < 16; ++c) {
    size_t o = ((size_t)(b * 16 + c) << 16) + es;
    float hf = hfin[o];
    float Pp = Pprod[o];
    hfin[o] = H;                              // carry-in for chunk c
    H = fmaf(Pp, H, hf);
  }
}

__global__ __launch_bounds__(256)
void scan_pass3(const float* __restrict__ delta, const float* __restrict__ dbc,
                const unsigned short* __restrict__ xcb, const unsigned short* __restrict__ xzb,
                const float* __restrict__ A_log, const float* __restrict__ Dp,
                const float* __restrict__ hcarry, unsigned short* __restrict__ y_bf) {
  __shared__ float Bsh[1024];           // [64][16]
  __shared__ float Csh[1024];
  const int tid = threadIdx.x;
  const int bc = blockIdx.x >> 4;
  const int eg = blockIdx.x & 15;
  const int b = bc >> 4, c = bc & 15;
  const int e = eg * 256 + tid;
  const int mb = b * 1024 + c * 64;
  for (int i = tid; i < 1024; i += 256) {
    size_t base = (size_t)(mb + (i >> 4)) * 256 + (i & 15);
    Bsh[i] = dbc[base + 128];
    Csh[i] = dbc[base + 144];
  }
  __syncthreads();

  float A[16];
  const float4* al = reinterpret_cast<const float4*>(A_log + (size_t)e * 16);
#pragma unroll
  for (int q = 0; q < 4; ++q) {
    float4 v = al[q];
    A[q * 4 + 0] = -__expf(v.x); A[q * 4 + 1] = -__expf(v.y);
    A[q * 4 + 2] = -__expf(v.z); A[q * 4 + 3] = -__expf(v.w);
  }
  bool fastp = true;
#pragma unroll
  for (int s = 0; s < 16; ++s)
    fastp = fastp && (fabsf(A[s] + (float)(s + 1)) <= 1e-5f * (float)(s + 1));

  float h[16];
  const float* hp = hcarry + ((size_t)bc * 4096 + e) * 16;
#pragma unroll
  for (int s = 0; s < 16; ++s) h[s] = hp[s];
  const float Dv = Dp[e];

  if (fastp) {
    for (int ll = 0; ll < 64; ++ll) {
      const size_t m = (size_t)(mb + ll);
      float dl = delta[m * 4096 + e];
      float xcv = bf2f(xcb[m * 4096 + e]);
      float dxc = dl * xcv;
      float dA[16];
      dA_powers(__expf(-dl), dA);
      float y = 0.f;
#pragma unroll
      for (int s = 0; s < 16; ++s) {
        h[s] = fmaf(dA[s], h[s], Bsh[ll * 16 + s] * dxc);
        y = fmaf(h[s], Csh[ll * 16 + s], y);
      }
      float z = bf2f(xzb[m * 8192 + 4096 + e]);
      y = (y + xcv * Dv) * silu_f(z);
      y_bf[m * 4096 + e] = f2bf(y);
    }
  } else {
    for (int ll = 0; ll < 64; ++ll) {
      const size_t m = (size_t)(mb + ll);
      float dl = delta[m * 4096 + e];
      float xcv = bf2f(xcb[m * 4096 + e]);
      float dxc = dl * xcv;
      float y = 0.f;
#pragma unroll
      for (int s = 0; s < 16; ++s) {
        float dA = __expf(dl * A[s]);
        h[s] = fmaf(dA, h[s], Bsh[ll * 16 + s] * dxc);
        y = fmaf(h[s], Csh[ll * 16 + s], y);
      }
      float z = bf2f(xzb[m * 8192 + 4096 + e]);
      y = (y + xcv * Dv) * silu_f(z);
      y_bf[m * 4096 + e] = f2bf(y);
    }
  }
}

// ---------------------------------------------------------------------------
extern "C" void kernel_launch(void* const* d_in, const int* in_sizes, int n_in,
                              void* d_out, int out_size, void* d_ws, size_t ws_size,
                              hipStream_t stream) {
  const float* x      = (const float*)d_in[0];
  const float* W_in   = (const float*)d_in[1];
  const float* conv_w = (const float*)d_in[2];
  const float* conv_b = (const float*)d_in[3];
  const float* W_x    = (const float*)d_in[4];
  const float* W_dt   = (const float*)d_in[5];
  const float* b_dt   = (const float*)d_in[6];
  const float* A_log  = (const float*)d_in[7];
  const float* Dp     = (const float*)d_in[8];
  const float* W_out  = (const float*)d_in[9];
  float* out = (float*)d_out;
  char* ws = (char*)d_ws;

  // workspace (190,316,544 B; time-disjoint aliases):
  // slot0 (+0, 33.5 MB): Win_bf -> gpart2 -> delta (fp32)
  // +33554432 (16.8 MB): x_bf -> y_bf
  // +50331648 (16.8 MB): Wout_bf | +67108864 Wx_bf | +69206016 Wdt_bf
  // +70254592 (33.5 MB): xz_bf (bf16 [2048][8192])
  // +103809024: hfin (8.4 MB) | +145752064: Pprod (8.4 MB) | gpart4 bf16
  //   (33.5 MB at +103809024, after pass3; time-disjoint with hfin/Pprod)
  // +170917888 (16.8 MB): xc_bf | +187695104 dbc | +189792256 dt_bf
  unsigned short* Win_bf    = (unsigned short*)(ws + 0);
  float*          gpart2    = (float*)(ws + 0);
  float*          delta     = (float*)(ws + 0);
  unsigned short* x_bf      = (unsigned short*)(ws + 33554432);
  unsigned short* y_bf      = (unsigned short*)(ws + 33554432);   // alias (after GEMM1)
  unsigned short* Wout_bf   = (unsigned short*)(ws + 50331648);
  unsigned short* Wx_bf     = (unsigned short*)(ws + 67108864);
  unsigned short* Wdt_bf    = (unsigned short*)(ws + 69206016);
  unsigned short* xz_bf     = (unsigned short*)(ws + 70254592);
  unsigned short* gpart4    = (unsigned short*)(ws + 103809024);  // alias (after pass3)
  float*          hfin      = (float*)(ws + 103809024);           // scan-time
  float*          Pprod     = (float*)(ws + 145752064);
  unsigned short* xc_bf     = (unsigned short*)(ws + 170917888);
  float*          dbc       = (float*)(ws + 187695104);
  unsigned short* dt_bf     = (unsigned short*)(ws + 189792256);

  // fused casts (x, W_in, W_out, W_dt, Wx-pad)
  cast_all<<<30208, 256, 0, stream>>>(x, W_in, W_out, W_dt, W_x,
                                      x_bf, Win_bf, Wout_bf, Wdt_bf, Wx_bf);

  // GEMM1: xz_bf[2048][8192] = x @ W_in^T (bf16 output)
  gemm_bt_8ph<unsigned short><<<256, 512, 0, stream>>>(x_bf, Win_bf, xz_bf, 2048, 8192, 2048, 8, 2048);

  // conv + silu -> xc_bf
  conv_silu_kernel<<<8192, 256, 0, stream>>>(xz_bf, conv_w, conv_b, xc_bf);

  // GEMM2 (split-K=8): partials[8][2048][256] = xc @ Wx_pad^T
  gemm_bt<<<dim3(2, 16, 8), 256, 0, stream>>>(xc_bf, Wx_bf, gpart2, 2048, 256, 4096, 512, nullptr);
  reduce8_dbc<<<2048, 256, 0, stream>>>(gpart2, dbc, dt_bf);

  // GEMM3 (+fused bias+softplus): delta[2048][4096] = sp(dt @ W_dt^T + b_dt)
  gemm_bt<<<dim3(32, 16, 1), 256, 0, stream>>>(dt_bf, Wdt_bf, delta, 2048, 4096, 128, 128, b_dt);

  // SSM scan: chunked two-pass
  scan_pass1<<<512, 256, 0, stream>>>(delta, dbc, xc_bf, A_log, hfin, Pprod);
  scan_pass2<<<512, 256, 0, stream>>>(hfin, Pprod);
  scan_pass3<<<512, 256, 0, stream>>>(delta, dbc, xc_bf, xz_bf, A_log, Dp, hfin, y_bf);

  // GEMM4 (8ph, split-K=4, bf16 partials): partials[4][2048][2048] = y @ W_out^T
  gemm_bt_8ph<unsigned short><<<dim3(64, 1, 4), 512, 0, stream>>>(y_bf, Wout_bf, gpart4, 2048, 2048, 4096, 8, 1024);
  reduce4_out_bf<<<4096, 256, 0, stream>>>(gpart4, out);
}